// Round 9
// baseline (1032.613 us; speedup 1.0000x reference)
//
#include <hip/hip_runtime.h>

#define B_ 256
#define T_ 128
#define E_ 512
#define H_ 512
#define NG 2048   // 4*H_
#define NB 256    // persistent blocks
#define NT 512    // threads per block (8 waves)

typedef __attribute__((ext_vector_type(8))) short bf16x8;
typedef __attribute__((ext_vector_type(4))) float f32x4;
typedef unsigned long long u64;

__device__ __forceinline__ short f2bf(float f) {
  union { float f; unsigned u; } x; x.f = f;
  unsigned r = x.u + 0x7FFFu + ((x.u >> 16) & 1u);  // RNE
  return (short)(r >> 16);
}
__device__ __forceinline__ float bf2f(short s) {
  union { unsigned u; float f; } x;
  x.u = ((unsigned)(unsigned short)s) << 16; return x.f;
}
__device__ __forceinline__ float sigm(float x) { return 1.0f / (1.0f + __expf(-x)); }
__device__ __forceinline__ float tanh_(float x) {
  float cx = fminf(fmaxf(x, -9.f), 9.f);
  float e = __expf(2.f * cx);
  return (e - 1.f) / (e + 1.f);
}

// ---- Wt[j][k] = bf16( k<512 ? Wx[k][j] : Uh[k-512][j] )
__global__ __launch_bounds__(256) void prep_w(const float* __restrict__ Wx,
                                              const float* __restrict__ Uh,
                                              short* __restrict__ Wt) {
  __shared__ float tile[64][65];
  const int k0 = blockIdx.x * 64;   // 16 blocks
  const int j0 = blockIdx.y * 64;   // 32 blocks
  const int tx = threadIdx.x & 63, ty = threadIdx.x >> 6;
#pragma unroll
  for (int r = 0; r < 16; ++r) {
    int k = k0 + r * 4 + ty;
    float v = (k < 512) ? Wx[(size_t)k * NG + j0 + tx]
                        : Uh[(size_t)(k - 512) * NG + j0 + tx];
    tile[r * 4 + ty][tx] = v;
  }
  __syncthreads();
#pragma unroll
  for (int r = 0; r < 16; ++r) {
    int j = j0 + r * 4 + ty;
    Wt[(size_t)j * 1024 + k0 + tx] = f2bf(tile[tx][r * 4 + ty]);
  }
}

// ---- xs[t][b][e] = bf16(emb[captions[b][t]][e]); padding_idx=0 row zeroed
__global__ __launch_bounds__(256) void stage_x(const int* __restrict__ captions,
                                               const float* __restrict__ emb,
                                               short* __restrict__ xs) {
  const int bid = blockIdx.x;          // = t*B_ + b
  const int t = bid >> 8, b = bid & 255;
  const int tok = captions[b * T_ + t];
  short* o = xs + (size_t)bid * E_;
  const float* src = emb + (size_t)tok * E_;
  int e0 = threadIdx.x, e1 = threadIdx.x + 256;
  if (tok) { o[e0] = f2bf(src[e0]); o[e1] = f2bf(src[e1]); }
  else     { o[e0] = 0;             o[e1] = 0; }
}

// ---- persistent kernel: all 128 LSTM steps.
// R7 structure (fabric-spread groups mg=bid>>5, pinned weights, padded 1-round
// reduction) with IN-BAND TAGGED h exchange replacing the flag protocol:
// h words are u64 {tag=t+1 | 2xbf16}; the data IS the readiness signal.
// Writer: gate math -> tagged relaxed-agent stores -> DONE (no vmcnt ack, no
// SYNC3, no flag hop). Reader: issue all 32 loads in flight, then parallel
// retry rounds on stale words only. Safety (monotonic tags, no ABA): a block
// stores h_{t} only after its kq2/3 waves register-loaded ALL of h_{t-1}
// (barrier-ordered); a block reaches the t+2 store (same buffer as h_t) only
// after verifying all of h_{t+1}, which implies every block consumed h_t.
// Buffers are memset to 0 every launch: tag 0 never matches, no replay state.
__global__ __launch_bounds__(NT, 2) void lstm_all(
    const short* __restrict__ xs,   // [T][B][E] bf16
    const short* __restrict__ Wt,   // [2048][1024] bf16
    const float* __restrict__ bx, const float* __restrict__ bu,
    u64* __restrict__ hb0, u64* __restrict__ hb1) {
  __shared__ float red[2][3][4][16][20];   // mh,slot(kq1..3),gate,row,col20 = 30 KB
  __shared__ float gbuf[2][4][16][20];     // 10 KB

  const int tid = threadIdx.x;
  const int wid = tid >> 6, lane = tid & 63;
  const int l15 = lane & 15, l4 = lane >> 4;
  const int kq = wid >> 1, mh = wid & 1;
  const int mg = blockIdx.x >> 5, jt = blockIdx.x & 31;   // cross-XCD groups
  const int j0 = jt * 16;
  const int rA = mg * 32 + mh * 16 + l15;

  // ---- persistent B fragments, pinned on-chip (VGPR/AGPR)
  bf16x8 bfr[4][8];
#pragma unroll
  for (int g = 0; g < 4; ++g) {
    const short* wp = Wt + (size_t)(g * 512 + j0 + l15) * 1024 + kq * 256 + l4 * 8;
#pragma unroll
    for (int ks = 0; ks < 8; ++ks)
      bfr[g][ks] = *(const bf16x8*)(wp + ks * 32);
  }
#pragma unroll
  for (int g = 0; g < 4; ++g)
#pragma unroll
    for (int ks = 0; ks < 8; ++ks)
      asm volatile("" : "+v"(bfr[g][ks]));   // sever rematerialization

  // ---- per-thread gate-math constants & cell state (one cell per thread)
  const int mh2 = tid >> 8, rr = (tid >> 4) & 15, jj = tid & 15;
  const int J = j0 + jj;
  const float bi  = bx[J] + bu[J];
  const float bf_ = bx[512 + J] + bu[512 + J];
  const float bo  = bx[1024 + J] + bu[1024 + J];
  const float bg  = bx[1536 + J] + bu[1536 + J];
  const int Rrow = mg * 32 + mh2 * 16 + rr;
  float c_reg = 0.f;

  for (int t = 0; t < T_; ++t) {
    u64* hout = (t & 1) ? hb1 : hb0;
    const u64* hin = (t & 1) ? hb0 : hb1;   // h_{t-1} in buffer (t-1)&1

    f32x4 acc[4] = {{0,0,0,0},{0,0,0,0},{0,0,0,0},{0,0,0,0}};

    if (kq < 2) {
      // ---- x half of K (always ready)
      const short* ab = xs + ((size_t)t * B_ + rA) * E_ + kq * 256 + l4 * 8;
      bf16x8 af[8];
#pragma unroll
      for (int ks = 0; ks < 8; ++ks) af[ks] = *(const bf16x8*)(ab + ks * 32);
#pragma unroll
      for (int ks = 0; ks < 8; ++ks)
#pragma unroll
        for (int g = 0; g < 4; ++g)
          acc[g] = __builtin_amdgcn_mfma_f32_16x16x32_bf16(af[ks], bfr[g][ks], acc[g], 0, 0, 0);
    } else if (t > 0) {
      // ---- h half: tagged words; all 32 loads in flight, parallel retry
      const u64* hp = hin + (size_t)rA * 256 + (kq - 2) * 128 + l4 * 4;
      const unsigned exp_ = (unsigned)t;
      u64 w[32];
#pragma unroll
      for (int ks = 0; ks < 8; ++ks)
#pragma unroll
        for (int i = 0; i < 4; ++i)
          w[ks * 4 + i] = __hip_atomic_load(hp + ks * 16 + i,
                                            __ATOMIC_RELAXED, __HIP_MEMORY_SCOPE_AGENT);
      {
        bool ok = false;
        while (!ok) {
          ok = true;
#pragma unroll
          for (int q = 0; q < 32; ++q) {
            if ((unsigned)(w[q] >> 32) != exp_) {
              w[q] = __hip_atomic_load(hp + (q >> 2) * 16 + (q & 3),
                                       __ATOMIC_RELAXED, __HIP_MEMORY_SCOPE_AGENT);
              ok = false;
            }
          }
        }
      }
#pragma unroll
      for (int ks = 0; ks < 8; ++ks) {
        union { bf16x8 v; unsigned u[4]; } fa;
#pragma unroll
        for (int i = 0; i < 4; ++i) fa.u[i] = (unsigned)w[ks * 4 + i];
#pragma unroll
        for (int g = 0; g < 4; ++g)
          acc[g] = __builtin_amdgcn_mfma_f32_16x16x32_bf16(fa.v, bfr[g][ks], acc[g], 0, 0, 0);
      }
    }
    // (kq>=2, t==0: h_{-1}=0 -> acc stays 0)

    // ---- partials to LDS (kq 1..3), one round
    if (kq) {
#pragma unroll
      for (int g = 0; g < 4; ++g)
#pragma unroll
        for (int r = 0; r < 4; ++r)
          red[mh][kq - 1][g][l4 * 4 + r][l15] = acc[g][r];
    }
    __syncthreads();                                   // SYNC1
    if (kq == 0) {
#pragma unroll
      for (int g = 0; g < 4; ++g)
#pragma unroll
        for (int r = 0; r < 4; ++r)
          gbuf[mh][g][l4 * 4 + r][l15] = acc[g][r]
              + red[mh][0][g][l4 * 4 + r][l15]
              + red[mh][1][g][l4 * 4 + r][l15]
              + red[mh][2][g][l4 * 4 + r][l15];
    }
    __syncthreads();                                   // SYNC2

    // ---- gate math by all 512 threads; c in regs; tagged h store, then done
    {
      float iv = gbuf[mh2][0][rr][jj] + bi;
      float fv = gbuf[mh2][1][rr][jj] + bf_;
      float ov = gbuf[mh2][2][rr][jj] + bo;
      float gv = gbuf[mh2][3][rr][jj] + bg;
      float cn = sigm(fv) * c_reg + sigm(iv) * tanh_(gv);
      c_reg = cn;
      unsigned mine = (unsigned)(unsigned short)f2bf(sigm(ov) * tanh_(cn));
      unsigned other = (unsigned)__shfl_xor((int)mine, 1, 64);
      if (!(jj & 1)) {
        u64 val = (((u64)(unsigned)(t + 1)) << 32) | (u64)(mine | (other << 16));
        __hip_atomic_store(hout + Rrow * 256 + (J >> 1), val,
                           __ATOMIC_RELAXED, __HIP_MEMORY_SCOPE_AGENT);
      }
    }
    // no ack, no barrier, no flag: the tag travels with the data.
  }
}

// ---- out[b,:] = normalize( h_last[b,:] @ fcW + fcb ); h is tagged u64 pairs
__global__ __launch_bounds__(256) void final_fc(const u64* __restrict__ h,
                                                const float* __restrict__ fcW,
                                                const float* __restrict__ fcb,
                                                float* __restrict__ out) {
  const int b = blockIdx.x, tid = threadIdx.x;
  __shared__ float hrow[512];
  __shared__ float red[256];
  {
    u64 w = h[(size_t)b * 256 + tid];
    hrow[tid * 2]     = bf2f((short)(w & 0xFFFF));
    hrow[tid * 2 + 1] = bf2f((short)((w >> 16) & 0xFFFF));
  }
  __syncthreads();
  float a0 = fcb[tid], a1 = fcb[tid + 256];
  for (int k = 0; k < 512; ++k) {
    float hv = hrow[k];
    a0 += hv * fcW[(size_t)k * 512 + tid];
    a1 += hv * fcW[(size_t)k * 512 + tid + 256];
  }
  red[tid] = a0 * a0 + a1 * a1;
  __syncthreads();
  for (int s = 128; s > 0; s >>= 1) {
    if (tid < s) red[tid] += red[tid + s];
    __syncthreads();
  }
  float scale = 1.0f / fmaxf(sqrtf(red[0]), 1e-12f);
  out[(size_t)b * 512 + tid] = a0 * scale;
  out[(size_t)b * 512 + tid + 256] = a1 * scale;
}

extern "C" void kernel_launch(void* const* d_in, const int* in_sizes, int n_in,
                              void* d_out, int out_size, void* d_ws, size_t ws_size,
                              hipStream_t stream) {
  const int*   captions = (const int*)d_in[0];
  const float* emb      = (const float*)d_in[1];
  const float* Wx       = (const float*)d_in[2];
  const float* bx       = (const float*)d_in[3];
  const float* Uh       = (const float*)d_in[4];
  const float* bu       = (const float*)d_in[5];
  const float* fcW      = (const float*)d_in[6];
  const float* fcb      = (const float*)d_in[7];
  float* out = (float*)d_out;

  char* ws = (char*)d_ws;
  size_t off = 0;
  auto alloc = [&](size_t bytes) {
    char* p = ws + off;
    off += (bytes + 255) & ~(size_t)255;
    return p;
  };
  short* Wt  = (short*)alloc((size_t)NG * 1024 * 2);     // 4 MB
  short* xs  = (short*)alloc((size_t)T_ * B_ * E_ * 2);  // 32 MB
  u64*   hb0 = (u64*)alloc((size_t)B_ * 256 * 8);        // 512 KB tagged
  u64*   hb1 = (u64*)alloc((size_t)B_ * 256 * 8);

  // tags gate all h reads -> must be zeroed every launch (graph replay safe)
  hipMemsetAsync(hb0, 0, (size_t)B_ * 256 * 8, stream);
  hipMemsetAsync(hb1, 0, (size_t)B_ * 256 * 8, stream);

  prep_w<<<dim3(16, 32), 256, 0, stream>>>(Wx, Uh, Wt);
  stage_x<<<T_ * B_, 256, 0, stream>>>(captions, emb, xs);

  void* kargs[] = {(void*)&xs, (void*)&Wt, (void*)&bx, (void*)&bu,
                   (void*)&hb0, (void*)&hb1};
  hipLaunchCooperativeKernel((const void*)lstm_all, dim3(NB), dim3(NT),
                             kargs, 0, stream);

  // t=127 wrote buffer 127&1 = hb1
  final_fc<<<B_, 256, 0, stream>>>(hb1, fcW, fcb, out);
}

// Round 10
// 914.262 us; speedup vs baseline: 1.1294x; 1.1294x over previous
//
#include <hip/hip_runtime.h>

#define B_ 256
#define T_ 128
#define E_ 512
#define H_ 512
#define NG 2048   // 4*H_
#define NB 256    // persistent blocks
#define NT 512    // threads per block (8 waves)

typedef __attribute__((ext_vector_type(8))) short bf16x8;
typedef __attribute__((ext_vector_type(4))) float f32x4;
typedef unsigned long long u64;

__device__ __forceinline__ short f2bf(float f) {
  union { float f; unsigned u; } x; x.f = f;
  unsigned r = x.u + 0x7FFFu + ((x.u >> 16) & 1u);  // RNE
  return (short)(r >> 16);
}
__device__ __forceinline__ float bf2f(short s) {
  union { unsigned u; float f; } x;
  x.u = ((unsigned)(unsigned short)s) << 16; return x.f;
}
__device__ __forceinline__ float sigm(float x) { return 1.0f / (1.0f + __expf(-x)); }
__device__ __forceinline__ float tanh_(float x) {
  float cx = fminf(fmaxf(x, -9.f), 9.f);
  float e = __expf(2.f * cx);
  return (e - 1.f) / (e + 1.f);
}

// ---- Wt[j][k] = bf16( k<512 ? Wx[k][j] : Uh[k-512][j] )
__global__ __launch_bounds__(256) void prep_w(const float* __restrict__ Wx,
                                              const float* __restrict__ Uh,
                                              short* __restrict__ Wt) {
  __shared__ float tile[64][65];
  const int k0 = blockIdx.x * 64;   // 16 blocks
  const int j0 = blockIdx.y * 64;   // 32 blocks
  const int tx = threadIdx.x & 63, ty = threadIdx.x >> 6;
#pragma unroll
  for (int r = 0; r < 16; ++r) {
    int k = k0 + r * 4 + ty;
    float v = (k < 512) ? Wx[(size_t)k * NG + j0 + tx]
                        : Uh[(size_t)(k - 512) * NG + j0 + tx];
    tile[r * 4 + ty][tx] = v;
  }
  __syncthreads();
#pragma unroll
  for (int r = 0; r < 16; ++r) {
    int j = j0 + r * 4 + ty;
    Wt[(size_t)j * 1024 + k0 + tx] = f2bf(tile[tx][r * 4 + ty]);
  }
}

// ---- xs[t][b][e] = bf16(emb[captions[b][t]][e]); padding_idx=0 row zeroed
__global__ __launch_bounds__(256) void stage_x(const int* __restrict__ captions,
                                               const float* __restrict__ emb,
                                               short* __restrict__ xs) {
  const int bid = blockIdx.x;          // = t*B_ + b
  const int t = bid >> 8, b = bid & 255;
  const int tok = captions[b * T_ + t];
  short* o = xs + (size_t)bid * E_;
  const float* src = emb + (size_t)tok * E_;
  int e0 = threadIdx.x, e1 = threadIdx.x + 256;
  if (tok) { o[e0] = f2bf(src[e0]); o[e1] = f2bf(src[e1]); }
  else     { o[e0] = 0;             o[e1] = 0; }
}

// ---- persistent kernel: all 128 LSTM steps.
// Topology: mg = bid>>5 (groups span XCDs -> fabric load-balanced), jt = bid&31.
// Sync: FLAGS for cheap readiness polling (1 line/writer-wave) + TAGS on data
// for validity (retries ~0, bounded). Per step ONE raw s_barrier (no vmcnt
// drain). Phase A: kq0/1 x-MFMA; kq2/3 poll slice flags, tagged-load h_{t-1},
// verify, MFMA; kq0/1/3 write partials to parity LDS slots; lgkmcnt; barrier.
// Phase B: kq2 (per mh) reduces in regs, gate math, tagged h stores, then its
// per-wave flag — program-order issue only, NO vmcnt ack, NO second barrier.
// Safety: X's phase-B h_{t+2} stores are barrier-ordered after X's kq2 AND kq3
// phase-A verifications of t+2 data, which transitively imply all 32 group
// blocks fully consumed h_t (R8 induction). Tags monotonic; hb/flags zeroed
// every launch (stale tags from a prior replay would alias expected values).
__global__ __launch_bounds__(NT, 2) void lstm_all(
    const short* __restrict__ xs,   // [T][B][E] bf16
    const short* __restrict__ Wt,   // [2048][1024] bf16
    const float* __restrict__ bx, const float* __restrict__ bu,
    u64* __restrict__ hb0, u64* __restrict__ hb1,
    unsigned* __restrict__ flags) { // [8 mg][2 mh][32 jt] stride 32 uints
  __shared__ float part[2][3][2][4][16][20];  // parity,slot(kq0,kq1,kq3),mh,gate,row,col20 = 60 KB

  const int tid = threadIdx.x;
  const int wid = tid >> 6, lane = tid & 63;
  const int l15 = lane & 15, l4 = lane >> 4;
  const int kq = wid >> 1, mh = wid & 1;
  const int mg = blockIdx.x >> 5, jt = blockIdx.x & 31;   // cross-XCD groups
  const int j0 = jt * 16;
  const int rA = mg * 32 + mh * 16 + l15;

  // ---- persistent B fragments, pinned on-chip (VGPR/AGPR)
  bf16x8 bfr[4][8];
#pragma unroll
  for (int g = 0; g < 4; ++g) {
    const short* wp = Wt + (size_t)(g * 512 + j0 + l15) * 1024 + kq * 256 + l4 * 8;
#pragma unroll
    for (int ks = 0; ks < 8; ++ks)
      bfr[g][ks] = *(const bf16x8*)(wp + ks * 32);
  }
#pragma unroll
  for (int g = 0; g < 4; ++g)
#pragma unroll
    for (int ks = 0; ks < 8; ++ks)
      asm volatile("" : "+v"(bfr[g][ks]));   // sever rematerialization

  // ---- kq2 gate constants: lane owns 4 cells (rows l4*4+r, col j0+l15)
  const int J = j0 + l15;
  const float bi  = bx[J] + bu[J];
  const float bf_ = bx[512 + J] + bu[512 + J];
  const float bo  = bx[1024 + J] + bu[1024 + J];
  const float bg  = bx[1536 + J] + bu[1536 + J];
  float c_reg[4] = {0.f, 0.f, 0.f, 0.f};

  unsigned* fl = flags + mg * 64 * 32;   // group base; flag (mh,jt) at [(mh*32+jt)*32]

  for (int t = 0; t < T_; ++t) {
    const int tp = t & 1;
    u64* hout = tp ? hb1 : hb0;
    const u64* hin = tp ? hb0 : hb1;   // h_{t-1} in buffer (t-1)&1

    f32x4 acc[4] = {{0,0,0,0},{0,0,0,0},{0,0,0,0},{0,0,0,0}};

    if (kq < 2) {
      // ---- x half of K (always ready)
      const short* ab = xs + ((size_t)t * B_ + rA) * E_ + kq * 256 + l4 * 8;
      bf16x8 af[8];
#pragma unroll
      for (int ks = 0; ks < 8; ++ks) af[ks] = *(const bf16x8*)(ab + ks * 32);
#pragma unroll
      for (int ks = 0; ks < 8; ++ks)
#pragma unroll
        for (int g = 0; g < 4; ++g)
          acc[g] = __builtin_amdgcn_mfma_f32_16x16x32_bf16(af[ks], bfr[g][ks], acc[g], 0, 0, 0);
    } else if (t > 0) {
      // ---- poll the 16 writer-wave flags of this (k-slice, mh) — 1 line each
      const unsigned* myfl = fl + (mh * 32 + (kq - 2) * 16 + l15) * 32;
      unsigned v = __hip_atomic_load(myfl, __ATOMIC_RELAXED, __HIP_MEMORY_SCOPE_AGENT);
      while (!__all((int)(v >= (unsigned)t))) {
        __builtin_amdgcn_s_sleep(1);
        v = __hip_atomic_load(myfl, __ATOMIC_RELAXED, __HIP_MEMORY_SCOPE_AGENT);
      }
      asm volatile("" ::: "memory");
      // ---- bulk tagged load (all 32 in flight), verify, rare parallel retry
      const u64* hp = hin + (size_t)rA * 256 + (kq - 2) * 128 + l4 * 4;
      const unsigned exp_ = (unsigned)t;
      u64 w[32];
#pragma unroll
      for (int ks = 0; ks < 8; ++ks)
#pragma unroll
        for (int i = 0; i < 4; ++i)
          w[ks * 4 + i] = __hip_atomic_load(hp + ks * 16 + i,
                                            __ATOMIC_RELAXED, __HIP_MEMORY_SCOPE_AGENT);
      {
        bool ok = false;
        while (!ok) {
          ok = true;
#pragma unroll
          for (int q = 0; q < 32; ++q) {
            if ((unsigned)(w[q] >> 32) != exp_) {
              w[q] = __hip_atomic_load(hp + (q >> 2) * 16 + (q & 3),
                                       __ATOMIC_RELAXED, __HIP_MEMORY_SCOPE_AGENT);
              ok = false;
            }
          }
        }
      }
#pragma unroll
      for (int ks = 0; ks < 8; ++ks) {
        union { bf16x8 v; unsigned u[4]; } fa;
#pragma unroll
        for (int i = 0; i < 4; ++i) fa.u[i] = (unsigned)w[ks * 4 + i];
#pragma unroll
        for (int g = 0; g < 4; ++g)
          acc[g] = __builtin_amdgcn_mfma_f32_16x16x32_bf16(fa.v, bfr[g][ks], acc[g], 0, 0, 0);
      }
    }
    // (kq>=2, t==0: h_{-1}=0 -> acc stays 0)

    // ---- partials to parity LDS slot; kq2 keeps its partial in registers
    if (kq != 2) {
      const int slot = (kq == 3) ? 2 : kq;
#pragma unroll
      for (int g = 0; g < 4; ++g)
#pragma unroll
        for (int r = 0; r < 4; ++r)
          part[tp][slot][mh][g][l4 * 4 + r][l15] = acc[g][r];
    }
    asm volatile("s_waitcnt lgkmcnt(0)" ::: "memory");
    __builtin_amdgcn_s_barrier();               // raw barrier: no vmcnt drain

    // ---- phase B: kq2 waves finalize alone; others run ahead into t+1
    if (kq == 2) {
#pragma unroll
      for (int g = 0; g < 4; ++g)
#pragma unroll
        for (int r = 0; r < 4; ++r)
          acc[g][r] += part[tp][0][mh][g][l4 * 4 + r][l15]
                     + part[tp][1][mh][g][l4 * 4 + r][l15]
                     + part[tp][2][mh][g][l4 * 4 + r][l15];
      unsigned hw[4];
#pragma unroll
      for (int r = 0; r < 4; ++r) {
        float iv = acc[0][r] + bi, fv = acc[1][r] + bf_;
        float ov = acc[2][r] + bo, gv = acc[3][r] + bg;
        float cn = sigm(fv) * c_reg[r] + sigm(iv) * tanh_(gv);
        c_reg[r] = cn;
        hw[r] = (unsigned)(unsigned short)f2bf(sigm(ov) * tanh_(cn));
      }
#pragma unroll
      for (int r = 0; r < 4; ++r) {
        unsigned other = (unsigned)__shfl_xor((int)hw[r], 1, 64);
        if (!(l15 & 1)) {
          const int R = mg * 32 + mh * 16 + l4 * 4 + r;
          u64 val = (((u64)(unsigned)(t + 1)) << 32) | (u64)(hw[r] | (other << 16));
          __hip_atomic_store(hout + (size_t)R * 256 + (J >> 1), val,
                             __ATOMIC_RELAXED, __HIP_MEMORY_SCOPE_AGENT);
        }
      }
      // per-wave flag: issued after stores in program order; tags cover
      // any fabric store reordering (reader retries the straggler words).
      if (lane == 0)
        __hip_atomic_store(fl + (mh * 32 + jt) * 32, (unsigned)(t + 1),
                           __ATOMIC_RELAXED, __HIP_MEMORY_SCOPE_AGENT);
    }
  }
}

// ---- out[b,:] = normalize( h_last[b,:] @ fcW + fcb ); h is tagged u64 pairs
__global__ __launch_bounds__(256) void final_fc(const u64* __restrict__ h,
                                                const float* __restrict__ fcW,
                                                const float* __restrict__ fcb,
                                                float* __restrict__ out) {
  const int b = blockIdx.x, tid = threadIdx.x;
  __shared__ float hrow[512];
  __shared__ float red[256];
  {
    u64 w = h[(size_t)b * 256 + tid];
    hrow[tid * 2]     = bf2f((short)(w & 0xFFFF));
    hrow[tid * 2 + 1] = bf2f((short)((w >> 16) & 0xFFFF));
  }
  __syncthreads();
  float a0 = fcb[tid], a1 = fcb[tid + 256];
  for (int k = 0; k < 512; ++k) {
    float hv = hrow[k];
    a0 += hv * fcW[(size_t)k * 512 + tid];
    a1 += hv * fcW[(size_t)k * 512 + tid + 256];
  }
  red[tid] = a0 * a0 + a1 * a1;
  __syncthreads();
  for (int s = 128; s > 0; s >>= 1) {
    if (tid < s) red[tid] += red[tid + s];
    __syncthreads();
  }
  float scale = 1.0f / fmaxf(sqrtf(red[0]), 1e-12f);
  out[(size_t)b * 512 + tid] = a0 * scale;
  out[(size_t)b * 512 + tid + 256] = a1 * scale;
}

extern "C" void kernel_launch(void* const* d_in, const int* in_sizes, int n_in,
                              void* d_out, int out_size, void* d_ws, size_t ws_size,
                              hipStream_t stream) {
  const int*   captions = (const int*)d_in[0];
  const float* emb      = (const float*)d_in[1];
  const float* Wx       = (const float*)d_in[2];
  const float* bx       = (const float*)d_in[3];
  const float* Uh       = (const float*)d_in[4];
  const float* bu       = (const float*)d_in[5];
  const float* fcW      = (const float*)d_in[6];
  const float* fcb      = (const float*)d_in[7];
  float* out = (float*)d_out;

  char* ws = (char*)d_ws;
  size_t off = 0;
  auto alloc = [&](size_t bytes) {
    char* p = ws + off;
    off += (bytes + 255) & ~(size_t)255;
    return p;
  };
  short*    Wt    = (short*)alloc((size_t)NG * 1024 * 2);     // 4 MB
  short*    xs    = (short*)alloc((size_t)T_ * B_ * E_ * 2);  // 32 MB
  u64*      hb0   = (u64*)alloc((size_t)B_ * 256 * 8);        // 512 KB tagged
  u64*      hb1   = (u64*)alloc((size_t)B_ * 256 * 8);
  unsigned* flags = (unsigned*)alloc(8 * 64 * 32 * 4);        // 64 KB strided

  // zero every launch: stale tags/flags from a prior graph replay would alias
  // this launch's expected values and hand readers stale h data.
  hipMemsetAsync(hb0, 0, (size_t)B_ * 256 * 8, stream);
  hipMemsetAsync(hb1, 0, (size_t)B_ * 256 * 8, stream);
  hipMemsetAsync(flags, 0, 8 * 64 * 32 * 4, stream);

  prep_w<<<dim3(16, 32), 256, 0, stream>>>(Wx, Uh, Wt);
  stage_x<<<T_ * B_, 256, 0, stream>>>(captions, emb, xs);

  void* kargs[] = {(void*)&xs, (void*)&Wt, (void*)&bx, (void*)&bu,
                   (void*)&hb0, (void*)&hb1, (void*)&flags};
  hipLaunchCooperativeKernel((const void*)lstm_all, dim3(NB), dim3(NT),
                             kargs, 0, stream);

  // t=127 wrote buffer 127&1 = hb1
  final_fc<<<B_, 256, 0, stream>>>(hb1, fcW, fcb, out);
}

// Round 11
// 695.048 us; speedup vs baseline: 1.4857x; 1.3154x over previous
//
#include <hip/hip_runtime.h>

#define B_ 256
#define T_ 128
#define E_ 512
#define H_ 512
#define NG 2048   // 4*H_
#define NB 256    // persistent blocks
#define NT 512    // threads per block (8 waves)

typedef __attribute__((ext_vector_type(8))) short bf16x8;
typedef __attribute__((ext_vector_type(4))) float f32x4;
typedef unsigned long long u64;

__device__ __forceinline__ short f2bf(float f) {
  union { float f; unsigned u; } x; x.f = f;
  unsigned r = x.u + 0x7FFFu + ((x.u >> 16) & 1u);  // RNE
  return (short)(r >> 16);
}
__device__ __forceinline__ float bf2f(short s) {
  union { unsigned u; float f; } x;
  x.u = ((unsigned)(unsigned short)s) << 16; return x.f;
}
__device__ __forceinline__ float sigm(float x) { return 1.0f / (1.0f + __expf(-x)); }
__device__ __forceinline__ float tanh_(float x) {
  float cx = fminf(fmaxf(x, -9.f), 9.f);
  float e = __expf(2.f * cx);
  return (e - 1.f) / (e + 1.f);
}

// ---- Wt[j][k] = bf16( k<512 ? Wx[k][j] : Uh[k-512][j] )
__global__ __launch_bounds__(256) void prep_w(const float* __restrict__ Wx,
                                              const float* __restrict__ Uh,
                                              short* __restrict__ Wt) {
  __shared__ float tile[64][65];
  const int k0 = blockIdx.x * 64;   // 16 blocks
  const int j0 = blockIdx.y * 64;   // 32 blocks
  const int tx = threadIdx.x & 63, ty = threadIdx.x >> 6;
#pragma unroll
  for (int r = 0; r < 16; ++r) {
    int k = k0 + r * 4 + ty;
    float v = (k < 512) ? Wx[(size_t)k * NG + j0 + tx]
                        : Uh[(size_t)(k - 512) * NG + j0 + tx];
    tile[r * 4 + ty][tx] = v;
  }
  __syncthreads();
#pragma unroll
  for (int r = 0; r < 16; ++r) {
    int j = j0 + r * 4 + ty;
    Wt[(size_t)j * 1024 + k0 + tx] = f2bf(tile[tx][r * 4 + ty]);
  }
}

// ---- xs[t][b][e] = bf16(emb[captions[b][t]][e]); padding_idx=0 row zeroed
__global__ __launch_bounds__(256) void stage_x(const int* __restrict__ captions,
                                               const float* __restrict__ emb,
                                               short* __restrict__ xs) {
  const int bid = blockIdx.x;          // = t*B_ + b
  const int t = bid >> 8, b = bid & 255;
  const int tok = captions[b * T_ + t];
  short* o = xs + (size_t)bid * E_;
  const float* src = emb + (size_t)tok * E_;
  int e0 = threadIdx.x, e1 = threadIdx.x + 256;
  if (tok) { o[e0] = f2bf(src[e0]); o[e1] = f2bf(src[e1]); }
  else     { o[e0] = 0;             o[e1] = 0; }
}

// ---- persistent kernel: all 128 LSTM steps.
// Topology: mg = bid>>5 (groups span all 8 XCDs -> fabric load-balanced).
// Protocol (R7's, proven): writer stores untagged packed-u32 h, vmcnt(0) ACK,
// THEN flag (one 128-B line per writer wave). Readers poll flags, then one
// bulk u64 load pass — no tag verify, no retry flood.
// Structure (R9's): ONE raw s_barrier per step. Phase A: kq0/1 x-MFMA; kq2/3
// poll their slice's 16 flags + load h_{t-1} + MFMA; kq0/1/3 write partials
// to parity-indexed LDS; lgkmcnt(0); s_barrier. Phase B: kq2 waves alone
// reduce (own partial in regs) + gate math + h store + ack + flag, while
// kq0/1 run ahead into step t+1's x-MFMA and kq3 starts polling t+1 flags.
// Overwrite safety (2 buffers): flag=t+1 from Y implies Y passed barrier(t),
// hence Y fully consumed h_{t-1}; X stores h_{t+1} (same buffer as h_{t-1})
// only after its kq2 AND kq3 observed all 32 flags >= t+1 (barrier-ordered).
// Flags zeroed every launch (they gate all h reads; graph-replay safe).
__global__ __launch_bounds__(NT, 2) void lstm_all(
    const short* __restrict__ xs,   // [T][B][E] bf16
    const short* __restrict__ Wt,   // [2048][1024] bf16
    const float* __restrict__ bx, const float* __restrict__ bu,
    unsigned* __restrict__ hb0, unsigned* __restrict__ hb1,
    unsigned* __restrict__ flags) { // [8 mg][2 mh][32 jt] stride 32 uints
  __shared__ float part[2][3][2][4][16][20];  // parity,slot(kq0,kq1,kq3),mh,gate,row,col20 = 60 KB

  const int tid = threadIdx.x;
  const int wid = tid >> 6, lane = tid & 63;
  const int l15 = lane & 15, l4 = lane >> 4;
  const int kq = wid >> 1, mh = wid & 1;
  const int mg = blockIdx.x >> 5, jt = blockIdx.x & 31;   // cross-XCD groups
  const int j0 = jt * 16;
  const int rA = mg * 32 + mh * 16 + l15;

  // ---- persistent B fragments, pinned on-chip (VGPR/AGPR)
  bf16x8 bfr[4][8];
#pragma unroll
  for (int g = 0; g < 4; ++g) {
    const short* wp = Wt + (size_t)(g * 512 + j0 + l15) * 1024 + kq * 256 + l4 * 8;
#pragma unroll
    for (int ks = 0; ks < 8; ++ks)
      bfr[g][ks] = *(const bf16x8*)(wp + ks * 32);
  }
#pragma unroll
  for (int g = 0; g < 4; ++g)
#pragma unroll
    for (int ks = 0; ks < 8; ++ks)
      asm volatile("" : "+v"(bfr[g][ks]));   // sever rematerialization

  // ---- kq2 gate constants: lane owns 4 cells (rows l4*4+r, col j0+l15)
  const int J = j0 + l15;
  const float bi  = bx[J] + bu[J];
  const float bf_ = bx[512 + J] + bu[512 + J];
  const float bo  = bx[1024 + J] + bu[1024 + J];
  const float bg  = bx[1536 + J] + bu[1536 + J];
  float c_reg[4] = {0.f, 0.f, 0.f, 0.f};

  unsigned* fl = flags + mg * 64 * 32;   // flag (mh,jt) at [(mh*32+jt)*32]

  for (int t = 0; t < T_; ++t) {
    const int tp = t & 1;
    unsigned* hout = tp ? hb1 : hb0;
    const unsigned* hin = tp ? hb0 : hb1;   // h_{t-1} in buffer (t-1)&1

    f32x4 acc[4] = {{0,0,0,0},{0,0,0,0},{0,0,0,0},{0,0,0,0}};

    if (kq < 2) {
      // ---- x half of K (always ready)
      const short* ab = xs + ((size_t)t * B_ + rA) * E_ + kq * 256 + l4 * 8;
      bf16x8 af[8];
#pragma unroll
      for (int ks = 0; ks < 8; ++ks) af[ks] = *(const bf16x8*)(ab + ks * 32);
#pragma unroll
      for (int ks = 0; ks < 8; ++ks)
#pragma unroll
        for (int g = 0; g < 4; ++g)
          acc[g] = __builtin_amdgcn_mfma_f32_16x16x32_bf16(af[ks], bfr[g][ks], acc[g], 0, 0, 0);
    } else if (t > 0) {
      // ---- poll the 16 writer-wave flags of this (k-slice, mh) — 1 line each
      const unsigned* myfl = fl + (mh * 32 + (kq - 2) * 16 + l15) * 32;
      unsigned v = __hip_atomic_load(myfl, __ATOMIC_RELAXED, __HIP_MEMORY_SCOPE_AGENT);
      while (!__all((int)(v >= (unsigned)t))) {
        __builtin_amdgcn_s_sleep(1);
        v = __hip_atomic_load(myfl, __ATOMIC_RELAXED, __HIP_MEMORY_SCOPE_AGENT);
      }
      asm volatile("" ::: "memory");
      // ---- one bulk load pass (flags are ack-gated: data is valid)
      const u64* hp = (const u64*)hin + (size_t)rA * 128 + (kq - 2) * 64 + l4 * 2;
      u64 w[16];
#pragma unroll
      for (int ks = 0; ks < 8; ++ks) {
        w[ks * 2]     = __hip_atomic_load(hp + ks * 8,     __ATOMIC_RELAXED, __HIP_MEMORY_SCOPE_AGENT);
        w[ks * 2 + 1] = __hip_atomic_load(hp + ks * 8 + 1, __ATOMIC_RELAXED, __HIP_MEMORY_SCOPE_AGENT);
      }
#pragma unroll
      for (int ks = 0; ks < 8; ++ks) {
        union { bf16x8 v; unsigned u[4]; } fa;
        fa.u[0] = (unsigned)w[ks * 2];
        fa.u[1] = (unsigned)(w[ks * 2] >> 32);
        fa.u[2] = (unsigned)w[ks * 2 + 1];
        fa.u[3] = (unsigned)(w[ks * 2 + 1] >> 32);
#pragma unroll
        for (int g = 0; g < 4; ++g)
          acc[g] = __builtin_amdgcn_mfma_f32_16x16x32_bf16(fa.v, bfr[g][ks], acc[g], 0, 0, 0);
      }
    }
    // (kq>=2, t==0: h_{-1}=0 -> acc stays 0)

    // ---- partials to parity LDS slot; kq2 keeps its partial in registers
    if (kq != 2) {
      const int slot = (kq == 3) ? 2 : kq;
#pragma unroll
      for (int g = 0; g < 4; ++g)
#pragma unroll
        for (int r = 0; r < 4; ++r)
          part[tp][slot][mh][g][l4 * 4 + r][l15] = acc[g][r];
    }
    asm volatile("s_waitcnt lgkmcnt(0)" ::: "memory");
    __builtin_amdgcn_s_barrier();               // raw barrier: no vmcnt drain

    // ---- phase B: kq2 waves finalize alone; others run ahead into t+1
    if (kq == 2) {
#pragma unroll
      for (int g = 0; g < 4; ++g)
#pragma unroll
        for (int r = 0; r < 4; ++r)
          acc[g][r] += part[tp][0][mh][g][l4 * 4 + r][l15]
                     + part[tp][1][mh][g][l4 * 4 + r][l15]
                     + part[tp][2][mh][g][l4 * 4 + r][l15];
      unsigned hw[4];
#pragma unroll
      for (int r = 0; r < 4; ++r) {
        float iv = acc[0][r] + bi, fv = acc[1][r] + bf_;
        float ov = acc[2][r] + bo, gv = acc[3][r] + bg;
        float cn = sigm(fv) * c_reg[r] + sigm(iv) * tanh_(gv);
        c_reg[r] = cn;
        hw[r] = (unsigned)(unsigned short)f2bf(sigm(ov) * tanh_(cn));
      }
#pragma unroll
      for (int r = 0; r < 4; ++r) {
        unsigned other = (unsigned)__shfl_xor((int)hw[r], 1, 64);
        if (!(l15 & 1)) {
          const int R = mg * 32 + mh * 16 + l4 * 4 + r;
          __hip_atomic_store(hout + (size_t)R * 256 + (J >> 1),
                             hw[r] | (other << 16),
                             __ATOMIC_RELAXED, __HIP_MEMORY_SCOPE_AGENT);
        }
      }
      // ACK then flag: readers that see the flag see the data (R7 protocol).
      asm volatile("s_waitcnt vmcnt(0)" ::: "memory");
      if (lane == 0)
        __hip_atomic_store(fl + (mh * 32 + jt) * 32, (unsigned)(t + 1),
                           __ATOMIC_RELAXED, __HIP_MEMORY_SCOPE_AGENT);
    }
  }
}

// ---- out[b,:] = normalize( h_last[b,:] @ fcW + fcb ); h is packed u32{2xbf16}
__global__ __launch_bounds__(256) void final_fc(const unsigned* __restrict__ h,
                                                const float* __restrict__ fcW,
                                                const float* __restrict__ fcb,
                                                float* __restrict__ out) {
  const int b = blockIdx.x, tid = threadIdx.x;
  __shared__ float hrow[512];
  __shared__ float red[256];
  {
    unsigned w = h[(size_t)b * 256 + tid];
    hrow[tid * 2]     = bf2f((short)(w & 0xFFFF));
    hrow[tid * 2 + 1] = bf2f((short)(w >> 16));
  }
  __syncthreads();
  float a0 = fcb[tid], a1 = fcb[tid + 256];
  for (int k = 0; k < 512; ++k) {
    float hv = hrow[k];
    a0 += hv * fcW[(size_t)k * 512 + tid];
    a1 += hv * fcW[(size_t)k * 512 + tid + 256];
  }
  red[tid] = a0 * a0 + a1 * a1;
  __syncthreads();
  for (int s = 128; s > 0; s >>= 1) {
    if (tid < s) red[tid] += red[tid + s];
    __syncthreads();
  }
  float scale = 1.0f / fmaxf(sqrtf(red[0]), 1e-12f);
  out[(size_t)b * 512 + tid] = a0 * scale;
  out[(size_t)b * 512 + tid + 256] = a1 * scale;
}

extern "C" void kernel_launch(void* const* d_in, const int* in_sizes, int n_in,
                              void* d_out, int out_size, void* d_ws, size_t ws_size,
                              hipStream_t stream) {
  const int*   captions = (const int*)d_in[0];
  const float* emb      = (const float*)d_in[1];
  const float* Wx       = (const float*)d_in[2];
  const float* bx       = (const float*)d_in[3];
  const float* Uh       = (const float*)d_in[4];
  const float* bu       = (const float*)d_in[5];
  const float* fcW      = (const float*)d_in[6];
  const float* fcb      = (const float*)d_in[7];
  float* out = (float*)d_out;

  char* ws = (char*)d_ws;
  size_t off = 0;
  auto alloc = [&](size_t bytes) {
    char* p = ws + off;
    off += (bytes + 255) & ~(size_t)255;
    return p;
  };
  short*    Wt    = (short*)alloc((size_t)NG * 1024 * 2);     // 4 MB
  short*    xs    = (short*)alloc((size_t)T_ * B_ * E_ * 2);  // 32 MB
  unsigned* hb0   = (unsigned*)alloc((size_t)B_ * 256 * 4);   // 256 KB packed
  unsigned* hb1   = (unsigned*)alloc((size_t)B_ * 256 * 4);
  unsigned* flags = (unsigned*)alloc(8 * 64 * 32 * 4);        // 64 KB strided

  // flags gate all h reads -> zero every launch (graph replay safe)
  hipMemsetAsync(flags, 0, 8 * 64 * 32 * 4, stream);

  prep_w<<<dim3(16, 32), 256, 0, stream>>>(Wx, Uh, Wt);
  stage_x<<<T_ * B_, 256, 0, stream>>>(captions, emb, xs);

  void* kargs[] = {(void*)&xs, (void*)&Wt, (void*)&bx, (void*)&bu,
                   (void*)&hb0, (void*)&hb1, (void*)&flags};
  hipLaunchCooperativeKernel((const void*)lstm_all, dim3(NB), dim3(NT),
                             kargs, 0, stream);

  // t=127 wrote buffer 127&1 = hb1
  final_fc<<<B_, 256, 0, stream>>>(hb1, fcW, fcb, out);
}

// Round 13
// 694.630 us; speedup vs baseline: 1.4866x; 1.0006x over previous
//
#include <hip/hip_runtime.h>

#define B_ 256
#define T_ 128
#define E_ 512
#define H_ 512
#define NG 2048   // 4*H_
#define NB 256    // persistent blocks
#define NT 512    // threads per block (8 waves)

typedef __attribute__((ext_vector_type(8))) short bf16x8;
typedef __attribute__((ext_vector_type(4))) float f32x4;
typedef unsigned long long u64;

__device__ __forceinline__ short f2bf(float f) {
  union { float f; unsigned u; } x; x.f = f;
  unsigned r = x.u + 0x7FFFu + ((x.u >> 16) & 1u);  // RNE
  return (short)(r >> 16);
}
__device__ __forceinline__ float bf2f(short s) {
  union { unsigned u; float f; } x;
  x.u = ((unsigned)(unsigned short)s) << 16; return x.f;
}
__device__ __forceinline__ float sigm(float x) { return 1.0f / (1.0f + __expf(-x)); }
__device__ __forceinline__ float tanh_(float x) {
  float cx = fminf(fmaxf(x, -9.f), 9.f);
  float e = __expf(2.f * cx);
  return (e - 1.f) / (e + 1.f);
}

// ---- Wt[j][k] = bf16( k<512 ? Wx[k][j] : Uh[k-512][j] )
__global__ __launch_bounds__(256) void prep_w(const float* __restrict__ Wx,
                                              const float* __restrict__ Uh,
                                              short* __restrict__ Wt) {
  __shared__ float tile[64][65];
  const int k0 = blockIdx.x * 64;   // 16 blocks
  const int j0 = blockIdx.y * 64;   // 32 blocks
  const int tx = threadIdx.x & 63, ty = threadIdx.x >> 6;
#pragma unroll
  for (int r = 0; r < 16; ++r) {
    int k = k0 + r * 4 + ty;
    float v = (k < 512) ? Wx[(size_t)k * NG + j0 + tx]
                        : Uh[(size_t)(k - 512) * NG + j0 + tx];
    tile[r * 4 + ty][tx] = v;
  }
  __syncthreads();
#pragma unroll
  for (int r = 0; r < 16; ++r) {
    int j = j0 + r * 4 + ty;
    Wt[(size_t)j * 1024 + k0 + tx] = f2bf(tile[tx][r * 4 + ty]);
  }
}

// ---- xs[t][b][e] = bf16(emb[captions[b][t]][e]); padding_idx=0 row zeroed
__global__ __launch_bounds__(256) void stage_x(const int* __restrict__ captions,
                                               const float* __restrict__ emb,
                                               short* __restrict__ xs) {
  const int bid = blockIdx.x;          // = t*B_ + b
  const int t = bid >> 8, b = bid & 255;
  const int tok = captions[b * T_ + t];
  short* o = xs + (size_t)bid * E_;
  const float* src = emb + (size_t)tok * E_;
  int e0 = threadIdx.x, e1 = threadIdx.x + 256;
  if (tok) { o[e0] = f2bf(src[e0]); o[e1] = f2bf(src[e1]); }
  else     { o[e0] = 0;             o[e1] = 0; }
}

// ---- persistent kernel: all 128 LSTM steps. (R10 protocol, verbatim; plus
// chunked reader pipeline, poll backoff, vectorized LDS partials.)
// Topology: mg = bid>>5 (groups span all 8 XCDs -> fabric load-balanced).
// Protocol: writer stores untagged packed-u32 h, vmcnt(0) ACK, THEN flag (one
// 128-B line per writer wave). Readers poll flags (escalating s_sleep backoff)
// then bulk-load — in TWO 8-writer chunks, overlapping the first chunk's
// loads+MFMAs with the second chunk's stragglers.
// Per step: ONE raw s_barrier. Phase A: kq0/1 x-MFMA; kq2/3 chunked wait/load/
// MFMA of h_{t-1}; kq0/1/3 write f32x4 partials to parity LDS; lgkmcnt(0);
// s_barrier. Phase B: kq2 reduces (b128 reads) + gates + h store + vmcnt(0)
// ack + flag, while kq0/1 run ahead into t+1 and kq3 polls t+1 flags.
// Overwrite safety (2 buffers): flag=t+1 from Y implies Y passed barrier(t),
// hence Y fully consumed h_{t-1}; X stores h_{t+1} (same buffer as h_{t-1})
// only after its kq2 AND kq3 observed all 32 flags >= t+1 (barrier-ordered).
// Flags zeroed every launch (they gate all h reads; graph-replay safe).
__global__ __launch_bounds__(NT, 2) void lstm_all(
    const short* __restrict__ xs,   // [T][B][E] bf16
    const short* __restrict__ Wt,   // [2048][1024] bf16
    const float* __restrict__ bx, const float* __restrict__ bu,
    unsigned* __restrict__ hb0, unsigned* __restrict__ hb1,
    unsigned* __restrict__ flags) { // [8 mg][2 mh][32 jt] stride 32 uints
  // [parity][slot(kq0,kq1,kq3)][mh][gate][l4][l15] of f32x4 -> 48 KB, b128 I/O
  __shared__ f32x4 part[2][3][2][4][4][16];

  const int tid = threadIdx.x;
  const int wid = tid >> 6, lane = tid & 63;
  const int l15 = lane & 15, l4 = lane >> 4;
  const int kq = wid >> 1, mh = wid & 1;
  const int mg = blockIdx.x >> 5, jt = blockIdx.x & 31;   // cross-XCD groups
  const int j0 = jt * 16;
  const int rA = mg * 32 + mh * 16 + l15;

  // ---- persistent B fragments, pinned on-chip (VGPR/AGPR)
  bf16x8 bfr[4][8];
#pragma unroll
  for (int g = 0; g < 4; ++g) {
    const short* wp = Wt + (size_t)(g * 512 + j0 + l15) * 1024 + kq * 256 + l4 * 8;
#pragma unroll
    for (int ks = 0; ks < 8; ++ks)
      bfr[g][ks] = *(const bf16x8*)(wp + ks * 32);
  }
#pragma unroll
  for (int g = 0; g < 4; ++g)
#pragma unroll
    for (int ks = 0; ks < 8; ++ks)
      asm volatile("" : "+v"(bfr[g][ks]));   // sever rematerialization

  // ---- kq2 gate constants: lane owns 4 cells (rows l4*4+r, col j0+l15)
  const int J = j0 + l15;
  const float bi  = bx[J] + bu[J];
  const float bf_ = bx[512 + J] + bu[512 + J];
  const float bo  = bx[1024 + J] + bu[1024 + J];
  const float bg  = bx[1536 + J] + bu[1536 + J];
  float c_reg[4] = {0.f, 0.f, 0.f, 0.f};

  unsigned* fl = flags + mg * 64 * 32;   // flag (mh,jt) at [(mh*32+jt)*32]

  for (int t = 0; t < T_; ++t) {
    const int tp = t & 1;
    unsigned* hout = tp ? hb1 : hb0;
    const unsigned* hin = tp ? hb0 : hb1;   // h_{t-1} in buffer (t-1)&1

    f32x4 acc[4] = {{0,0,0,0},{0,0,0,0},{0,0,0,0},{0,0,0,0}};

    if (kq < 2) {
      // ---- x half of K (always ready)
      const short* ab = xs + ((size_t)t * B_ + rA) * E_ + kq * 256 + l4 * 8;
      bf16x8 af[8];
#pragma unroll
      for (int ks = 0; ks < 8; ++ks) af[ks] = *(const bf16x8*)(ab + ks * 32);
#pragma unroll
      for (int ks = 0; ks < 8; ++ks)
#pragma unroll
        for (int g = 0; g < 4; ++g)
          acc[g] = __builtin_amdgcn_mfma_f32_16x16x32_bf16(af[ks], bfr[g][ks], acc[g], 0, 0, 0);
    } else if (t > 0) {
      // ---- chunked wait/load/MFMA over the 16 writer waves of this slice.
      // chunk0 = writers l15 0..7 (cols 0..127 of the slice), chunk1 = 8..15.
      const unsigned thr = (unsigned)t;
      const unsigned* myfl = fl + (mh * 32 + (kq - 2) * 16 + l15) * 32;
      const u64* hp = (const u64*)hin + (size_t)rA * 128 + (kq - 2) * 64 + l4 * 2;
      unsigned v = __hip_atomic_load(myfl, __ATOMIC_RELAXED, __HIP_MEMORY_SCOPE_AGENT);
      int spin = 0;
      while (!__all((int)((l15 >= 8) | (v >= thr)))) {
        if (spin++ < 4) __builtin_amdgcn_s_sleep(1);
        else            __builtin_amdgcn_s_sleep(8);
        v = __hip_atomic_load(myfl, __ATOMIC_RELAXED, __HIP_MEMORY_SCOPE_AGENT);
      }
      asm volatile("" ::: "memory");
      u64 w[16];
#pragma unroll
      for (int ks = 0; ks < 4; ++ks) {
        w[ks * 2]     = __hip_atomic_load(hp + ks * 8,     __ATOMIC_RELAXED, __HIP_MEMORY_SCOPE_AGENT);
        w[ks * 2 + 1] = __hip_atomic_load(hp + ks * 8 + 1, __ATOMIC_RELAXED, __HIP_MEMORY_SCOPE_AGENT);
      }
#pragma unroll
      for (int ks = 0; ks < 4; ++ks) {
        union { bf16x8 v; unsigned u[4]; } fa;
        fa.u[0] = (unsigned)w[ks * 2];
        fa.u[1] = (unsigned)(w[ks * 2] >> 32);
        fa.u[2] = (unsigned)w[ks * 2 + 1];
        fa.u[3] = (unsigned)(w[ks * 2 + 1] >> 32);
#pragma unroll
        for (int g = 0; g < 4; ++g)
          acc[g] = __builtin_amdgcn_mfma_f32_16x16x32_bf16(fa.v, bfr[g][ks], acc[g], 0, 0, 0);
      }
      // chunk 1 (stragglers had the chunk-0 load+MFMA time to land)
      while (!__all((int)(v >= thr))) {
        if (spin++ < 4) __builtin_amdgcn_s_sleep(1);
        else            __builtin_amdgcn_s_sleep(8);
        v = __hip_atomic_load(myfl, __ATOMIC_RELAXED, __HIP_MEMORY_SCOPE_AGENT);
      }
      asm volatile("" ::: "memory");
#pragma unroll
      for (int ks = 4; ks < 8; ++ks) {
        w[ks * 2]     = __hip_atomic_load(hp + ks * 8,     __ATOMIC_RELAXED, __HIP_MEMORY_SCOPE_AGENT);
        w[ks * 2 + 1] = __hip_atomic_load(hp + ks * 8 + 1, __ATOMIC_RELAXED, __HIP_MEMORY_SCOPE_AGENT);
      }
#pragma unroll
      for (int ks = 4; ks < 8; ++ks) {
        union { bf16x8 v; unsigned u[4]; } fa;
        fa.u[0] = (unsigned)w[ks * 2];
        fa.u[1] = (unsigned)(w[ks * 2] >> 32);
        fa.u[2] = (unsigned)w[ks * 2 + 1];
        fa.u[3] = (unsigned)(w[ks * 2 + 1] >> 32);
#pragma unroll
        for (int g = 0; g < 4; ++g)
          acc[g] = __builtin_amdgcn_mfma_f32_16x16x32_bf16(fa.v, bfr[g][ks], acc[g], 0, 0, 0);
      }
    }
    // (kq>=2, t==0: h_{-1}=0 -> acc stays 0)

    // ---- partials to parity LDS slot (one ds_write_b128 per gate);
    //      kq2 keeps its partial in registers
    if (kq != 2) {
      const int slot = (kq == 3) ? 2 : kq;
#pragma unroll
      for (int g = 0; g < 4; ++g)
        part[tp][slot][mh][g][l4][l15] = acc[g];
    }
    asm volatile("s_waitcnt lgkmcnt(0)" ::: "memory");
    __builtin_amdgcn_s_barrier();               // raw barrier: no vmcnt drain

    // ---- phase B: kq2 waves finalize alone; others run ahead into t+1
    if (kq == 2) {
#pragma unroll
      for (int g = 0; g < 4; ++g)
        acc[g] += part[tp][0][mh][g][l4][l15]
                + part[tp][1][mh][g][l4][l15]
                + part[tp][2][mh][g][l4][l15];
      unsigned hw[4];
#pragma unroll
      for (int r = 0; r < 4; ++r) {
        float iv = acc[0][r] + bi, fv = acc[1][r] + bf_;
        float ov = acc[2][r] + bo, gv = acc[3][r] + bg;
        float cn = sigm(fv) * c_reg[r] + sigm(iv) * tanh_(gv);
        c_reg[r] = cn;
        hw[r] = (unsigned)(unsigned short)f2bf(sigm(ov) * tanh_(cn));
      }
#pragma unroll
      for (int r = 0; r < 4; ++r) {
        unsigned other = (unsigned)__shfl_xor((int)hw[r], 1, 64);
        if (!(l15 & 1)) {
          const int R = mg * 32 + mh * 16 + l4 * 4 + r;
          __hip_atomic_store(hout + (size_t)R * 256 + (J >> 1),
                             hw[r] | (other << 16),
                             __ATOMIC_RELAXED, __HIP_MEMORY_SCOPE_AGENT);
        }
      }
      // ACK then flag: readers that see the flag see the data (R10 protocol).
      asm volatile("s_waitcnt vmcnt(0)" ::: "memory");
      if (lane == 0)
        __hip_atomic_store(fl + (mh * 32 + jt) * 32, (unsigned)(t + 1),
                           __ATOMIC_RELAXED, __HIP_MEMORY_SCOPE_AGENT);
    }
  }
}

// ---- out[b,:] = normalize( h_last[b,:] @ fcW + fcb ); h is packed u32{2xbf16}
__global__ __launch_bounds__(256) void final_fc(const unsigned* __restrict__ h,
                                                const float* __restrict__ fcW,
                                                const float* __restrict__ fcb,
                                                float* __restrict__ out) {
  const int b = blockIdx.x, tid = threadIdx.x;
  __shared__ float hrow[512];
  __shared__ float red[256];
  {
    unsigned w = h[(size_t)b * 256 + tid];
    hrow[tid * 2]     = bf2f((short)(w & 0xFFFF));
    hrow[tid * 2 + 1] = bf2f((short)(w >> 16));
  }
  __syncthreads();
  float a0 = fcb[tid], a1 = fcb[tid + 256];
  for (int k = 0; k < 512; ++k) {
    float hv = hrow[k];
    a0 += hv * fcW[(size_t)k * 512 + tid];
    a1 += hv * fcW[(size_t)k * 512 + tid + 256];
  }
  red[tid] = a0 * a0 + a1 * a1;
  __syncthreads();
  for (int s = 128; s > 0; s >>= 1) {
    if (tid < s) red[tid] += red[tid + s];
    __syncthreads();
  }
  float scale = 1.0f / fmaxf(sqrtf(red[0]), 1e-12f);
  out[(size_t)b * 512 + tid] = a0 * scale;
  out[(size_t)b * 512 + tid + 256] = a1 * scale;
}

extern "C" void kernel_launch(void* const* d_in, const int* in_sizes, int n_in,
                              void* d_out, int out_size, void* d_ws, size_t ws_size,
                              hipStream_t stream) {
  const int*   captions = (const int*)d_in[0];
  const float* emb      = (const float*)d_in[1];
  const float* Wx       = (const float*)d_in[2];
  const float* bx       = (const float*)d_in[3];
  const float* Uh       = (const float*)d_in[4];
  const float* bu       = (const float*)d_in[5];
  const float* fcW      = (const float*)d_in[6];
  const float* fcb      = (const float*)d_in[7];
  float* out = (float*)d_out;

  char* ws = (char*)d_ws;
  size_t off = 0;
  auto alloc = [&](size_t bytes) {
    char* p = ws + off;
    off += (bytes + 255) & ~(size_t)255;
    return p;
  };
  short*    Wt    = (short*)alloc((size_t)NG * 1024 * 2);     // 4 MB
  short*    xs    = (short*)alloc((size_t)T_ * B_ * E_ * 2);  // 32 MB
  unsigned* hb0   = (unsigned*)alloc((size_t)B_ * 256 * 4);   // 256 KB packed
  unsigned* hb1   = (unsigned*)alloc((size_t)B_ * 256 * 4);
  unsigned* flags = (unsigned*)alloc(8 * 64 * 32 * 4);        // 64 KB strided

  // flags gate all h reads -> zero every launch (graph replay safe)
  hipMemsetAsync(flags, 0, 8 * 64 * 32 * 4, stream);

  prep_w<<<dim3(16, 32), 256, 0, stream>>>(Wx, Uh, Wt);
  stage_x<<<T_ * B_, 256, 0, stream>>>(captions, emb, xs);

  void* kargs[] = {(void*)&xs, (void*)&Wt, (void*)&bx, (void*)&bu,
                   (void*)&hb0, (void*)&hb1, (void*)&flags};
  hipLaunchCooperativeKernel((const void*)lstm_all, dim3(NB), dim3(NT),
                             kargs, 0, stream);

  // t=127 wrote buffer 127&1 = hb1
  final_fc<<<B_, 256, 0, stream>>>(hb1, fcW, fcb, out);
}